// Round 2
// baseline (559.709 us; speedup 1.0000x reference)
//
#include <hip/hip_runtime.h>
#include <math.h>

#define NB 36
#define HSTRIDE 37   // 36 bins padded: (37*t+b)%32 = (5t+b)%32 -> only 2-way lane aliasing (free)

// One THREAD per 32x32 patch, fully sequential per-patch math so every
// f32 rounding matches the numpy/XLA-CPU reference bit-for-bit:
//  - gradients/mag/binning in f32, contract(off), reference association order
//  - atan2 computed in f64 then rounded to f32  == correctly-rounded f32 atan2
//    (matches glibc/XLA atan2f except ~2^-29/pixel halfway coincidences)
//  - histogram accumulated per-bin in pixel order 0..1023 (matches scatter-add)
//  - smoothing + first-index argmax sequential in f32
// Output is one of 36 discrete angles -> any argmax flip fails; exactness is
// the whole game here.
__global__ __launch_bounds__(256, 1) void orient_kernel(
    const float* __restrict__ x,
    const float* __restrict__ gk,
    float* __restrict__ out)
{
#pragma clang fp contract(off)
  __shared__ float gks[1024];
  __shared__ float hist[256 * HSTRIDE];   // 37888 B + 4096 B = ~41 KB/block

  const int t = threadIdx.x;
  const int p = blockIdx.x * 256 + t;

  for (int i = t; i < 1024; i += 256) gks[i] = gk[i];
  float* __restrict__ h = &hist[t * HSTRIDE];
  #pragma unroll
  for (int b = 0; b < NB; ++b) h[b] = 0.0f;
  __syncthreads();

  const float* __restrict__ xp = x + (size_t)p * 1024;

  const float PI_F  = 3.14159265358979323846f;   // 0x40490FDB
  const float TPI_F = 6.28318530717958647692f;   // 0x40C90FDB

  // rolling 3-row window in registers
  float prv[32], cur[32], nxt[32];
  {
    const float4* v0 = (const float4*)xp;
    #pragma unroll
    for (int q = 0; q < 8; ++q) {
      float4 a = v0[q];
      cur[4*q+0]=a.x; cur[4*q+1]=a.y; cur[4*q+2]=a.z; cur[4*q+3]=a.w;
    }
    #pragma unroll
    for (int j = 0; j < 32; ++j) prv[j] = cur[j];   // row -1 = replicate row 0
    const float4* v1 = (const float4*)(xp + 32);
    #pragma unroll
    for (int q = 0; q < 8; ++q) {
      float4 a = v1[q];
      nxt[4*q+0]=a.x; nxt[4*q+1]=a.y; nxt[4*q+2]=a.z; nxt[4*q+3]=a.w;
    }
  }

  for (int r = 0; r < 32; ++r) {
    #pragma unroll
    for (int j = 0; j < 32; ++j) {
      float left  = (j == 0)  ? cur[0]  : cur[j-1];   // replicate pad
      float right = (j == 31) ? cur[31] : cur[j+1];
      float gx = 0.5f * (left - right);
      float gy = 0.5f * (prv[j] - nxt[j]);            // row r-1  minus row r+1
      float m2 = (gx*gx + gy*gy) + 1e-10f;            // ref association
      float mag = sqrtf(m2) * gks[r*32 + j];
      float ori = (float)atan2((double)gy, (double)gx);  // f64 -> CR f32 atan2
      float ob  = (36.0f * (ori + PI_F)) / TPI_F;     // ref association
      float fo  = floorf(ob);
      float wo1 = ob - fo;                            // pre-mod floor, like ref
      int   b0  = (int)fo;
      if (b0 >= NB) b0 -= NB;                         // ob can hit exactly 36.0
      h[b0] += (1.0f - wo1) * mag;                    // sequential pixel order
    }
    if (r < 31) {
      #pragma unroll
      for (int j = 0; j < 32; ++j) { prv[j] = cur[j]; cur[j] = nxt[j]; }
      if (r < 30) {
        const float4* v2 = (const float4*)(xp + (size_t)(r + 2) * 32);
        #pragma unroll
        for (int q = 0; q < 8; ++q) {
          float4 a = v2[q];
          nxt[4*q+0]=a.x; nxt[4*q+1]=a.y; nxt[4*q+2]=a.z; nxt[4*q+3]=a.w;
        }
      }
    }
  }

  // smooth (zero-padded [0.33,0.34,0.33]) + first-index argmax, sequential.
  // Skipping the /1024: exact power-of-2 scaling commutes with every f32
  // rounding below (no subnormals), so argmax is identical.
  float best = -INFINITY; int bi = 0;
  #pragma unroll
  for (int i = 0; i < NB; ++i) {
    float ll = (i > 0)      ? h[i-1] : 0.0f;
    float rr = (i < NB - 1) ? h[i+1] : 0.0f;
    float sm = (0.33f*ll + 0.34f*h[i]) + 0.33f*rr;    // ref association
    if (sm > best) { best = sm; bi = i; }             // strict > == first-index
  }
  float fi = (float)bi;
  out[p] = -((TPI_F * fi) / 36.0f - PI_F);
}

extern "C" void kernel_launch(void* const* d_in, const int* in_sizes, int n_in,
                              void* d_out, int out_size, void* d_ws, size_t ws_size,
                              hipStream_t stream) {
  const float* x  = (const float*)d_in[0];
  const float* gk = (const float*)d_in[1];
  float* out = (float*)d_out;
  const int B = in_sizes[0] / 1024;        // 65536 patches
  orient_kernel<<<B / 256, 256, 0, stream>>>(x, gk, out);
}